// Round 1
// baseline (112.855 us; speedup 1.0000x reference)
//
#include <hip/hip_runtime.h>
#include <math.h>

#define NCLS 81
#define NFG 80
#define KCOMP 11
#define NPROP 1000
#define MAXC 16384
#define DETS 100

// workspace layout (float indices)
#define WS_PROBS 0                      // [80][1000] class-major fg probs
#define WS_BOXES 80000                  // [80][1000][4] decoded+clipped
#define WS_COMPS 400000                 // [1000] comp score
#define WS_COMPI 401000                 // [1000] comp idx (as float)
#define WS_CSCORE 402000                // [MAXC] candidate scores
#define WS_CMETA  (402000 + MAXC)       // [MAXC] candidate meta (uint32)
#define WS_CNT    (402000 + 2*MAXC)     // int counter

__global__ __launch_bounds__(64) void prep_kernel(
    const float* __restrict__ cls_logits,
    const float* __restrict__ comp_logits,
    const float* __restrict__ boxreg,
    const float* __restrict__ props,
    float* __restrict__ ws)
{
    int n = blockIdx.x;
    int lane = threadIdx.x;
    if (n == 0 && lane == 0) ((int*)ws)[WS_CNT] = 0;

    // ---- class softmax (81 values, lanes hold c=lane and c=lane+64) ----
    float x0 = cls_logits[n * NCLS + lane];
    float x1 = (lane < NCLS - 64) ? cls_logits[n * NCLS + 64 + lane] : -INFINITY;
    float m = fmaxf(x0, x1);
    for (int off = 32; off; off >>= 1) m = fmaxf(m, __shfl_xor(m, off));
    float e0 = expf(x0 - m);
    float e1 = (lane < NCLS - 64) ? expf(x1 - m) : 0.0f;
    float s = e0 + e1;
    for (int off = 32; off; off >>= 1) s += __shfl_xor(s, off);
    if (lane >= 1)        ws[WS_PROBS + (lane - 1) * NPROP + n] = e0 / s;   // c = 1..63
    if (lane < NCLS - 64) ws[WS_PROBS + (lane + 63) * NPROP + n] = e1 / s;  // c = 64..80

    // ---- component softmax + fg max/argmax (first occurrence) ----
    float y = (lane < KCOMP) ? comp_logits[n * KCOMP + lane] : -INFINITY;
    float mc = y;
    for (int off = 32; off; off >>= 1) mc = fmaxf(mc, __shfl_xor(mc, off));
    float ec = (lane < KCOMP) ? expf(y - mc) : 0.0f;
    float sc = ec;
    for (int off = 32; off; off >>= 1) sc += __shfl_xor(sc, off);
    float p = (lane >= 1 && lane < KCOMP) ? ec / sc : -1.0f;
    int ci = lane;
    for (int off = 32; off; off >>= 1) {
        float po = __shfl_xor(p, off);
        int   io = __shfl_xor(ci, off);
        if (po > p || (po == p && io < ci)) { p = po; ci = io; }
    }
    if (lane == 0) {
        ws[WS_COMPS + n] = p;
        ws[WS_COMPI + n] = (float)ci;
    }

    // ---- box decode + clip for fg classes ----
    float px1 = props[n * 4 + 0], py1 = props[n * 4 + 1];
    float px2 = props[n * 4 + 2], py2 = props[n * 4 + 3];
    float w  = px2 - px1 + 1.0f, h = py2 - py1 + 1.0f;
    float cx = px1 + 0.5f * w,  cy = py1 + 0.5f * h;
    const float CLIPV = 4.135166556742356f; // log(1000/16)
    for (int rep = 0; rep < 2; ++rep) {
        int c = lane + 1 + rep * 64;
        if (c > NFG) break;
        const float* r = &boxreg[n * NCLS * 4 + c * 4];
        float dx = r[0] / 10.0f, dy = r[1] / 10.0f;
        float dw = fminf(r[2] / 5.0f, CLIPV), dh = fminf(r[3] / 5.0f, CLIPV);
        float pcx = dx * w + cx, pcy = dy * h + cy;
        float pw = expf(dw) * w, ph = expf(dh) * h;
        float bx1 = pcx - 0.5f * pw, by1 = pcy - 0.5f * ph;
        float bx2 = pcx + 0.5f * pw - 1.0f, by2 = pcy + 0.5f * ph - 1.0f;
        bx1 = fminf(fmaxf(bx1, 0.0f), 1332.0f);
        by1 = fminf(fmaxf(by1, 0.0f), 799.0f);
        bx2 = fminf(fmaxf(bx2, 0.0f), 1332.0f);
        by2 = fminf(fmaxf(by2, 0.0f), 799.0f);
        float* o = &ws[WS_BOXES + (((c - 1) * NPROP) + n) * 4];
        o[0] = bx1; o[1] = by1; o[2] = bx2; o[3] = by2;
    }
}

__global__ __launch_bounds__(64) void nms_kernel(float* __restrict__ ws)
{
    __shared__ float ls[1024];
    __shared__ int   ln[1024];
    __shared__ float ss[1024];
    __shared__ int   sn[1024];
    __shared__ float sb[1024][4];

    int cfg  = blockIdx.x;   // class c = cfg + 1
    int lane = threadIdx.x;
    const float* probs = &ws[WS_PROBS + cfg * NPROP];
    const float* boxes = &ws[WS_BOXES + cfg * NPROP * 4];

    // compact valid entries (preserves original n-order -> stable sort semantics)
    int cnt = 0;
    for (int base = 0; base < NPROP; base += 64) {
        int n = base + lane;
        float s = (n < NPROP) ? probs[n] : -1.0f;
        bool v = (n < NPROP) && (s > 0.05f);
        unsigned long long bm = __ballot(v);
        if (v) {
            int pos = cnt + __popcll(bm & ((1ull << lane) - 1ull));
            ls[pos] = s; ln[pos] = n;
        }
        cnt += __popcll(bm);
    }
    int M = cnt;
    __syncthreads();

    // rank sort (descending score, ties by compact index = original n order)
    for (int i = lane; i < M; i += 64) {
        float si = ls[i];
        int r = 0;
        for (int j = 0; j < M; ++j) {
            float sj = ls[j];
            r += (int)((sj > si) | ((sj == si) & (j < i)));
        }
        int ni = ln[i];
        ss[r] = si; sn[r] = ni;
        const float* bp = &boxes[ni * 4];
        sb[r][0] = bp[0]; sb[r][1] = bp[1]; sb[r][2] = bp[2]; sb[r][3] = bp[3];
    }
    __syncthreads();

    // greedy NMS: keep bits distributed 16 slots per lane (slot p -> lane p%64, bit p/64)
    unsigned int keep = 0;
    for (int k = 0; k < 16; ++k) {
        int p = lane + (k << 6);
        if (p < M) keep |= (1u << k);
    }
    for (int i = 0; i < M; ++i) {
        unsigned int ki = __shfl(keep, i & 63);
        if (!((ki >> (i >> 6)) & 1u)) continue;
        float ax1 = sb[i][0], ay1 = sb[i][1], ax2 = sb[i][2], ay2 = sb[i][3];
        float aarea = (ax2 - ax1 + 1.0f) * (ay2 - ay1 + 1.0f);
        unsigned int km = keep;
        while (km) {
            int k = __ffs(km) - 1; km &= km - 1;
            int p = lane + (k << 6);
            if (p <= i) continue;
            float bx1 = sb[p][0], by1 = sb[p][1], bx2 = sb[p][2], by2 = sb[p][3];
            float barea = (bx2 - bx1 + 1.0f) * (by2 - by1 + 1.0f);
            float lx = fmaxf(ax1, bx1), ly = fmaxf(ay1, by1);
            float rx = fminf(ax2, bx2), ry = fminf(ay2, by2);
            float iw = fmaxf(rx - lx + 1.0f, 0.0f), ih = fmaxf(ry - ly + 1.0f, 0.0f);
            float inter = iw * ih;
            float iou = inter / (aarea + barea - inter);
            if (iou > 0.5f) keep &= ~(1u << k);
        }
    }

    // append survivors to global candidate list
    int* cntp = &((int*)ws)[WS_CNT];
    for (int k = 0; k < 16; ++k) {
        int p = lane + (k << 6);
        bool v = (p < M) && ((keep >> k) & 1u);
        unsigned long long bm = __ballot(v);
        int cm = __popcll(bm);
        int base = 0;
        if (lane == 0 && cm) base = atomicAdd(cntp, cm);
        base = __shfl(base, 0);
        if (v) {
            int idx = base + __popcll(bm & ((1ull << lane) - 1ull));
            if (idx < MAXC) {
                ws[WS_CSCORE + idx] = ss[p];
                // meta = flat_sorted_index << 10 | original_n  (exact reference tie-break)
                ((unsigned int*)ws)[WS_CMETA + idx] =
                    (unsigned int)(((cfg * NPROP + p) << 10) | sn[p]);
            }
        }
    }
}

__global__ __launch_bounds__(256) void out_init_kernel(float* __restrict__ out, int out_size)
{
    int i = blockIdx.x * 256 + threadIdx.x;
    if (i < out_size) out[i] = (i >= 400 && i < 500) ? -1.0f : 0.0f;
}

__global__ __launch_bounds__(256) void topk_kernel(const float* __restrict__ ws,
                                                   float* __restrict__ out)
{
    int K = ((const int*)ws)[WS_CNT];
    if (K > MAXC) K = MAXC;
    int i = blockIdx.x * 256 + threadIdx.x;
    if (i >= K) return;

    const float* gs = &ws[WS_CSCORE];
    const unsigned int* gm = &((const unsigned int*)ws)[WS_CMETA];
    float si = gs[i];
    unsigned int mi = gm[i];
    int r = 0;
#pragma unroll 4
    for (int j = 0; j < K; ++j) {
        float sj = gs[j];
        unsigned int mj = gm[j];
        r += (int)((sj > si) | ((sj == si) & (mj < mi)));
    }
    if (r < DETS) {
        unsigned int n = mi & 1023u;
        unsigned int fp = mi >> 10;
        int c = (int)(fp / NPROP) + 1;
        const float* bp = &ws[WS_BOXES + (((c - 1) * NPROP) + n) * 4];
        out[r * 4 + 0] = bp[0];
        out[r * 4 + 1] = bp[1];
        out[r * 4 + 2] = bp[2];
        out[r * 4 + 3] = bp[3];
        out[400 + r] = si;
        out[500 + r] = ws[WS_COMPS + n];
        out[600 + r] = (float)c;
        out[700 + r] = ws[WS_COMPI + n];
    }
}

extern "C" void kernel_launch(void* const* d_in, const int* in_sizes, int n_in,
                              void* d_out, int out_size, void* d_ws, size_t ws_size,
                              hipStream_t stream)
{
    const float* cls  = (const float*)d_in[0];
    const float* comp = (const float*)d_in[1];
    const float* breg = (const float*)d_in[2];
    const float* prop = (const float*)d_in[3];
    float* ws  = (float*)d_ws;
    float* out = (float*)d_out;

    hipLaunchKernelGGL(prep_kernel, dim3(NPROP), dim3(64), 0, stream, cls, comp, breg, prop, ws);
    hipLaunchKernelGGL(nms_kernel, dim3(NFG), dim3(64), 0, stream, ws);
    int initBlocks = (out_size + 255) / 256;
    hipLaunchKernelGGL(out_init_kernel, dim3(initBlocks), dim3(256), 0, stream, out, out_size);
    // rank-select: K ~ a few thousand; 32 blocks x 256 threads covers up to 8192 candidates
    hipLaunchKernelGGL(topk_kernel, dim3((MAXC + 255) / 256), dim3(256), 0, stream, ws, out);
}

// Round 2
// 100.854 us; speedup vs baseline: 1.1190x; 1.1190x over previous
//
#include <hip/hip_runtime.h>
#include <math.h>

#define NCLS 81
#define NFG 80
#define KCOMP 11
#define NPROP 1000
#define MAXC 6144
#define DETS 100
#define TKB 8

// workspace layout (float indices)
#define WS_M      0                 // [1000] row max of class logits
#define WS_S      1000              // [1000] softmax denom
#define WS_COMPS  2000              // [1000] comp score
#define WS_COMPI  3000              // [1000] comp idx (as float)
#define WS_CAND   4096              // [MAXC][8]: key_lo, key_hi, x1,y1,x2,y2, comp_s, comp_i
#define WS_CNT    (4096 + MAXC*8)   // int counter

__global__ __launch_bounds__(64) void prep_kernel(
    const float* __restrict__ cls_logits,
    const float* __restrict__ comp_logits,
    float* __restrict__ ws,
    float* __restrict__ out, int out_size)
{
    int n = blockIdx.x;
    int lane = threadIdx.x;
    if (n == 0 && lane == 0) ((int*)ws)[WS_CNT] = 0;
    // output defaults (padded slots): score slots -1, everything else 0
    if (n < 13) {
        int oi = n * 64 + lane;
        if (oi < out_size) out[oi] = (oi >= 400 && oi < 500) ? -1.0f : 0.0f;
    }

    // ---- class softmax stats (81 values; lanes hold c=lane and c=lane+64) ----
    float x0 = cls_logits[n * NCLS + lane];
    float x1 = (lane < NCLS - 64) ? cls_logits[n * NCLS + 64 + lane] : -INFINITY;
    float m = fmaxf(x0, x1);
    for (int off = 32; off; off >>= 1) m = fmaxf(m, __shfl_xor(m, off));
    float s = expf(x0 - m) + ((lane < NCLS - 64) ? expf(x1 - m) : 0.0f);
    for (int off = 32; off; off >>= 1) s += __shfl_xor(s, off);
    if (lane == 0) { ws[WS_M + n] = m; ws[WS_S + n] = s; }

    // ---- component softmax + fg max/argmax (first occurrence) ----
    float y = (lane < KCOMP) ? comp_logits[n * KCOMP + lane] : -INFINITY;
    float mc = y;
    for (int off = 32; off; off >>= 1) mc = fmaxf(mc, __shfl_xor(mc, off));
    float ec = (lane < KCOMP) ? expf(y - mc) : 0.0f;
    float sc = ec;
    for (int off = 32; off; off >>= 1) sc += __shfl_xor(sc, off);
    float p = (lane >= 1 && lane < KCOMP) ? ec / sc : -1.0f;
    int ci = lane;
    for (int off = 32; off; off >>= 1) {
        float po = __shfl_xor(p, off);
        int   io = __shfl_xor(ci, off);
        if (po > p || (po == p && io < ci)) { p = po; ci = io; }
    }
    if (lane == 0) {
        ws[WS_COMPS + n] = p;
        ws[WS_COMPI + n] = (float)ci;
    }
}

__global__ __launch_bounds__(64) void nms_kernel(
    const float* __restrict__ cls_logits,
    const float* __restrict__ boxreg,
    const float* __restrict__ props,
    float* __restrict__ ws)
{
    __shared__ float ls[1024];
    __shared__ int   ln[1024];
    __shared__ float ss[1024];
    __shared__ int   sn[1024];
    __shared__ float sb[1024][4];

    int cfg  = blockIdx.x;   // class c = cfg + 1
    int c    = cfg + 1;
    int lane = threadIdx.x;

    // ---- compact valid entries (prob computed on the fly; preserves n-order) ----
    int cnt = 0;
    for (int base = 0; base < NPROP; base += 64) {
        int n = base + lane;
        bool v = false; float p = 0.0f;
        if (n < NPROP) {
            float x = cls_logits[n * NCLS + c];
            p = expf(x - ws[WS_M + n]) / ws[WS_S + n];
            v = p > 0.05f;
        }
        unsigned long long bm = __ballot(v);
        if (v) {
            int pos = cnt + __popcll(bm & ((1ull << lane) - 1ull));
            ls[pos] = p; ln[pos] = n;
        }
        cnt += __popcll(bm);
    }
    int M = cnt;
    __syncthreads();

    // ---- rank sort (descending score, ties by original n order) ----
    for (int i = lane; i < M; i += 64) {
        float si = ls[i];
        int r = 0;
        for (int j = 0; j < M; ++j) {
            float sj = ls[j];
            r += (int)((sj > si) | ((sj == si) & (j < i)));
        }
        ss[r] = si; sn[r] = ln[i];
    }
    __syncthreads();

    // ---- decode + clip boxes for the M sorted candidates only ----
    const float CLIPV = 4.135166556742356f; // log(1000/16)
    for (int p = lane; p < M; p += 64) {
        int n = sn[p];
        float4 r4 = ((const float4*)boxreg)[n * NCLS + c];
        float4 pr = ((const float4*)props)[n];
        float w  = pr.z - pr.x + 1.0f, h = pr.w - pr.y + 1.0f;
        float cx = pr.x + 0.5f * w,  cy = pr.y + 0.5f * h;
        float dx = r4.x / 10.0f, dy = r4.y / 10.0f;
        float dw = fminf(r4.z / 5.0f, CLIPV), dh = fminf(r4.w / 5.0f, CLIPV);
        float pcx = dx * w + cx, pcy = dy * h + cy;
        float pw = expf(dw) * w, ph = expf(dh) * h;
        sb[p][0] = fminf(fmaxf(pcx - 0.5f * pw, 0.0f), 1332.0f);
        sb[p][1] = fminf(fmaxf(pcy - 0.5f * ph, 0.0f), 799.0f);
        sb[p][2] = fminf(fmaxf(pcx + 0.5f * pw - 1.0f, 0.0f), 1332.0f);
        sb[p][3] = fminf(fmaxf(pcy + 0.5f * ph - 1.0f, 0.0f), 799.0f);
    }
    __syncthreads();

    // ---- greedy NMS: keep bits distributed, slot p -> lane p%64, bit p/64 ----
    unsigned int keep = 0;
    for (int k = 0; k < 16; ++k) {
        int p = lane + (k << 6);
        if (p < M) keep |= (1u << k);
    }
    for (int i = 0; i < M; ++i) {
        unsigned int ki = __shfl(keep, i & 63);
        if (!((ki >> (i >> 6)) & 1u)) continue;
        float ax1 = sb[i][0], ay1 = sb[i][1], ax2 = sb[i][2], ay2 = sb[i][3];
        float aarea = (ax2 - ax1 + 1.0f) * (ay2 - ay1 + 1.0f);
        unsigned int km = keep;
        while (km) {
            int k = __ffs(km) - 1; km &= km - 1;
            int p = lane + (k << 6);
            if (p <= i) continue;
            float bx1 = sb[p][0], by1 = sb[p][1], bx2 = sb[p][2], by2 = sb[p][3];
            float barea = (bx2 - bx1 + 1.0f) * (by2 - by1 + 1.0f);
            float lx = fmaxf(ax1, bx1), ly = fmaxf(ay1, by1);
            float rx = fminf(ax2, bx2), ry = fminf(ay2, by2);
            float iw = fmaxf(rx - lx + 1.0f, 0.0f), ih = fmaxf(ry - ly + 1.0f, 0.0f);
            float inter = iw * ih;
            float iou = inter / (aarea + barea - inter);
            if (iou > 0.5f) keep &= ~(1u << k);
        }
    }

    // ---- append survivor records to the global candidate list ----
    int* cntp = &((int*)ws)[WS_CNT];
    for (int k = 0; k < 16; ++k) {
        int p = lane + (k << 6);
        bool v = (p < M) && ((keep >> k) & 1u);
        unsigned long long bm = __ballot(v);
        int cm = __popcll(bm);
        int base = 0;
        if (lane == 0 && cm) base = atomicAdd(cntp, cm);
        base = __shfl(base, 0);
        if (v) {
            int idx = base + __popcll(bm & ((1ull << lane) - 1ull));
            if (idx < MAXC) {
                int n = sn[p];
                // meta = flat_sorted_index << 10 | original_n (reference tie-break)
                unsigned int meta = (unsigned int)(((cfg * NPROP + p) << 10) | n);
                // 64-bit sort key: score bits (positive floats are order-isomorphic)
                // in high word, ~meta in low word -> larger key = better.
                unsigned int khi = __float_as_uint(ss[p]);
                unsigned int klo = ~meta;
                float4* cp = (float4*)&ws[WS_CAND + idx * 8];
                cp[0] = make_float4(__uint_as_float(klo), __uint_as_float(khi),
                                    sb[p][0], sb[p][1]);
                cp[1] = make_float4(sb[p][2], sb[p][3],
                                    ws[WS_COMPS + n], ws[WS_COMPI + n]);
            }
        }
    }
}

__global__ __launch_bounds__(256) void topk_kernel(const float* __restrict__ ws,
                                                   float* __restrict__ out)
{
    __shared__ unsigned long long kk[MAXC];
    int K = ((const int*)ws)[WS_CNT];
    if (K > MAXC) K = MAXC;
    int tid = threadIdx.x, bid = blockIdx.x;
    if (bid * 256 >= K) return;  // whole block exits together (before any sync)

    for (int j = tid; j < K; j += 256)
        kk[j] = *(const unsigned long long*)&ws[WS_CAND + j * 8];
    __syncthreads();

    for (int i = bid * 256 + tid; i < K; i += TKB * 256) {
        unsigned long long ki = kk[i];
        int r = 0;
#pragma unroll 8
        for (int j = 0; j < K; ++j) {
            r += (int)(kk[j] > ki);
        }
        if (r < DETS) {
            const float4* cp = (const float4*)&ws[WS_CAND + i * 8];
            float4 a = cp[0], b = cp[1];
            unsigned int meta = ~__float_as_uint(a.x);
            float score = a.y;  // key_hi bits == score bits
            out[r * 4 + 0] = a.z;
            out[r * 4 + 1] = a.w;
            out[r * 4 + 2] = b.x;
            out[r * 4 + 3] = b.y;
            out[400 + r] = score;
            out[500 + r] = b.z;
            out[600 + r] = (float)((meta >> 10) / NPROP + 1);
            out[700 + r] = b.w;
        }
    }
}

extern "C" void kernel_launch(void* const* d_in, const int* in_sizes, int n_in,
                              void* d_out, int out_size, void* d_ws, size_t ws_size,
                              hipStream_t stream)
{
    const float* cls  = (const float*)d_in[0];
    const float* comp = (const float*)d_in[1];
    const float* breg = (const float*)d_in[2];
    const float* prop = (const float*)d_in[3];
    float* ws  = (float*)d_ws;
    float* out = (float*)d_out;

    hipLaunchKernelGGL(prep_kernel, dim3(NPROP), dim3(64), 0, stream,
                       cls, comp, ws, out, out_size);
    hipLaunchKernelGGL(nms_kernel, dim3(NFG), dim3(64), 0, stream,
                       cls, breg, prop, ws);
    hipLaunchKernelGGL(topk_kernel, dim3(TKB), dim3(256), 0, stream, ws, out);
}

// Round 3
// 83.808 us; speedup vs baseline: 1.3466x; 1.2034x over previous
//
#include <hip/hip_runtime.h>
#include <math.h>

#define NCLS 81
#define NFG 80
#define KCOMP 11
#define NPROP 1000
#define MAXC 6144
#define DETS 100
#define TKB 8

// workspace layout (float indices)
#define WS_M      0                 // [1000] row max of class logits
#define WS_S      1000              // [1000] softmax denom
#define WS_COMPS  2000              // [1000] comp score
#define WS_COMPI  3000              // [1000] comp idx (as float)
#define WS_CAND   4096              // [MAXC][8]: key_lo, key_hi, x1,y1,x2,y2, comp_s, comp_i
#define WS_CNT    (4096 + MAXC*8)   // int counter

__global__ __launch_bounds__(64) void prep_kernel(
    const float* __restrict__ cls_logits,
    const float* __restrict__ comp_logits,
    float* __restrict__ ws,
    float* __restrict__ out, int out_size)
{
    int n = blockIdx.x;
    int lane = threadIdx.x;
    if (n == 0 && lane == 0) ((int*)ws)[WS_CNT] = 0;
    // output defaults (padded slots): score slots -1, everything else 0
    if (n < 13) {
        int oi = n * 64 + lane;
        if (oi < out_size) out[oi] = (oi >= 400 && oi < 500) ? -1.0f : 0.0f;
    }

    // ---- class softmax stats (81 values; lanes hold c=lane and c=lane+64) ----
    float x0 = cls_logits[n * NCLS + lane];
    float x1 = (lane < NCLS - 64) ? cls_logits[n * NCLS + 64 + lane] : -INFINITY;
    float m = fmaxf(x0, x1);
    for (int off = 32; off; off >>= 1) m = fmaxf(m, __shfl_xor(m, off));
    float s = expf(x0 - m) + ((lane < NCLS - 64) ? expf(x1 - m) : 0.0f);
    for (int off = 32; off; off >>= 1) s += __shfl_xor(s, off);
    if (lane == 0) { ws[WS_M + n] = m; ws[WS_S + n] = s; }

    // ---- component softmax + fg max/argmax (first occurrence) ----
    float y = (lane < KCOMP) ? comp_logits[n * KCOMP + lane] : -INFINITY;
    float mc = y;
    for (int off = 32; off; off >>= 1) mc = fmaxf(mc, __shfl_xor(mc, off));
    float ec = (lane < KCOMP) ? expf(y - mc) : 0.0f;
    float sc = ec;
    for (int off = 32; off; off >>= 1) sc += __shfl_xor(sc, off);
    float p = (lane >= 1 && lane < KCOMP) ? ec / sc : -1.0f;
    int ci = lane;
    for (int off = 32; off; off >>= 1) {
        float po = __shfl_xor(p, off);
        int   io = __shfl_xor(ci, off);
        if (po > p || (po == p && io < ci)) { p = po; ci = io; }
    }
    if (lane == 0) {
        ws[WS_COMPS + n] = p;
        ws[WS_COMPI + n] = (float)ci;
    }
}

__global__ __launch_bounds__(64) void nms_kernel(
    const float* __restrict__ cls_logits,
    const float* __restrict__ boxreg,
    const float* __restrict__ props,
    float* __restrict__ ws)
{
    __shared__ float ls[1024];
    __shared__ int   ln[1024];
    __shared__ float ss[1024];
    __shared__ int   sn[1024];
    __shared__ float sb[1024][4];

    int cfg  = blockIdx.x;   // class c = cfg + 1
    int c    = cfg + 1;
    int lane = threadIdx.x;

    // ---- compute probs for all 16 rounds first (16 independent loads in flight) ----
    float pv[16];
#pragma unroll
    for (int t = 0; t < 16; ++t) {
        int n = t * 64 + lane;
        if (n < NPROP) {
            float x = cls_logits[n * NCLS + c];
            pv[t] = expf(x - ws[WS_M + n]) / ws[WS_S + n];
        } else {
            pv[t] = 0.0f;
        }
    }

    // ---- compact valid entries (preserves original n-order) ----
    int cnt = 0;
#pragma unroll
    for (int t = 0; t < 16; ++t) {
        int n = t * 64 + lane;
        bool v = (n < NPROP) && (pv[t] > 0.05f);
        unsigned long long bm = __ballot(v);
        if (v) {
            int pos = cnt + __popcll(bm & ((1ull << lane) - 1ull));
            ls[pos] = pv[t]; ln[pos] = n;
        }
        cnt += __popcll(bm);
    }
    int M = cnt;
    __syncthreads();

    // ---- rank sort (descending score, ties by original n order) ----
    for (int i = lane; i < M; i += 64) {
        float si = ls[i];
        int r = 0;
        for (int j = 0; j < M; ++j) {
            float sj = ls[j];
            r += (int)((sj > si) | ((sj == si) & (j < i)));
        }
        ss[r] = si; sn[r] = ln[i];
    }
    __syncthreads();

    // ---- decode + clip boxes for the M sorted candidates only ----
    const float CLIPV = 4.135166556742356f; // log(1000/16)
    for (int p = lane; p < M; p += 64) {
        int n = sn[p];
        float4 r4 = ((const float4*)boxreg)[n * NCLS + c];
        float4 pr = ((const float4*)props)[n];
        float w  = pr.z - pr.x + 1.0f, h = pr.w - pr.y + 1.0f;
        float cx = pr.x + 0.5f * w,  cy = pr.y + 0.5f * h;
        float dx = r4.x / 10.0f, dy = r4.y / 10.0f;
        float dw = fminf(r4.z / 5.0f, CLIPV), dh = fminf(r4.w / 5.0f, CLIPV);
        float pcx = dx * w + cx, pcy = dy * h + cy;
        float pw = expf(dw) * w, ph = expf(dh) * h;
        sb[p][0] = fminf(fmaxf(pcx - 0.5f * pw, 0.0f), 1332.0f);
        sb[p][1] = fminf(fmaxf(pcy - 0.5f * ph, 0.0f), 799.0f);
        sb[p][2] = fminf(fmaxf(pcx + 0.5f * pw - 1.0f, 0.0f), 1332.0f);
        sb[p][3] = fminf(fmaxf(pcy + 0.5f * ph - 1.0f, 0.0f), 799.0f);
    }
    __syncthreads();

    // ---- greedy NMS: keep bits distributed, slot p -> lane p%64, bit p/64 ----
    unsigned int keep = 0;
    for (int k = 0; k < 16; ++k) {
        int p = lane + (k << 6);
        if (p < M) keep |= (1u << k);
    }
    for (int i = 0; i < M; ++i) {
        unsigned int ki = __shfl(keep, i & 63);
        if (!((ki >> (i >> 6)) & 1u)) continue;
        float ax1 = sb[i][0], ay1 = sb[i][1], ax2 = sb[i][2], ay2 = sb[i][3];
        float aarea = (ax2 - ax1 + 1.0f) * (ay2 - ay1 + 1.0f);
        unsigned int km = keep;
        while (km) {
            int k = __ffs(km) - 1; km &= km - 1;
            int p = lane + (k << 6);
            if (p <= i) continue;
            float bx1 = sb[p][0], by1 = sb[p][1], bx2 = sb[p][2], by2 = sb[p][3];
            float barea = (bx2 - bx1 + 1.0f) * (by2 - by1 + 1.0f);
            float lx = fmaxf(ax1, bx1), ly = fmaxf(ay1, by1);
            float rx = fminf(ax2, bx2), ry = fminf(ay2, by2);
            float iw = fmaxf(rx - lx + 1.0f, 0.0f), ih = fmaxf(ry - ly + 1.0f, 0.0f);
            float inter = iw * ih;
            float iou = inter / (aarea + barea - inter);
            if (iou > 0.5f) keep &= ~(1u << k);
        }
    }

    // ---- append survivor records to the global candidate list ----
    int* cntp = &((int*)ws)[WS_CNT];
    for (int k = 0; k < 16; ++k) {
        int p = lane + (k << 6);
        bool v = (p < M) && ((keep >> k) & 1u);
        unsigned long long bm = __ballot(v);
        int cm = __popcll(bm);
        int base = 0;
        if (lane == 0 && cm) base = atomicAdd(cntp, cm);
        base = __shfl(base, 0);
        if (v) {
            int idx = base + __popcll(bm & ((1ull << lane) - 1ull));
            if (idx < MAXC) {
                int n = sn[p];
                // meta = flat_sorted_index << 10 | original_n (reference tie-break)
                unsigned int meta = (unsigned int)(((cfg * NPROP + p) << 10) | n);
                // 64-bit sort key: score bits (positive floats order-isomorphic)
                // in high word, ~meta in low word -> larger key = better.
                unsigned int khi = __float_as_uint(ss[p]);
                unsigned int klo = ~meta;
                float4* cp = (float4*)&ws[WS_CAND + idx * 8];
                cp[0] = make_float4(__uint_as_float(klo), __uint_as_float(khi),
                                    sb[p][0], sb[p][1]);
                cp[1] = make_float4(sb[p][2], sb[p][3],
                                    ws[WS_COMPS + n], ws[WS_COMPI + n]);
            }
        }
    }
}

__global__ __launch_bounds__(256) void topk_kernel(const float* __restrict__ ws,
                                                   float* __restrict__ out)
{
    __shared__ unsigned long long kk[MAXC];
    int K = ((const int*)ws)[WS_CNT];
    if (K > MAXC) K = MAXC;
    int tid = threadIdx.x, bid = blockIdx.x;
    if (bid * 256 >= K) return;  // whole block exits together (before any sync)

    for (int j = tid; j < K; j += 256)
        kk[j] = *(const unsigned long long*)&ws[WS_CAND + j * 8];
    __syncthreads();

    for (int i = bid * 256 + tid; i < K; i += TKB * 256) {
        unsigned long long ki = kk[i];
        int r = 0;
        int j = 0;
        // 16-deep register batches: 16 ds_read_b64 in flight before first use,
        // amortizes LDS latency to ~throughput. Static indices -> registers.
        for (; j + 16 <= K; j += 16) {
            unsigned long long a[16];
#pragma unroll
            for (int t = 0; t < 16; ++t) a[t] = kk[j + t];
#pragma unroll
            for (int t = 0; t < 16; ++t) r += (int)(a[t] > ki);
        }
        for (; j < K; ++j) r += (int)(kk[j] > ki);

        if (r < DETS) {
            const float4* cp = (const float4*)&ws[WS_CAND + i * 8];
            float4 a = cp[0], b = cp[1];
            unsigned int meta = ~__float_as_uint(a.x);
            float score = a.y;  // key_hi bits == score bits
            out[r * 4 + 0] = a.z;
            out[r * 4 + 1] = a.w;
            out[r * 4 + 2] = b.x;
            out[r * 4 + 3] = b.y;
            out[400 + r] = score;
            out[500 + r] = b.z;
            out[600 + r] = (float)((meta >> 10) / NPROP + 1);
            out[700 + r] = b.w;
        }
    }
}

extern "C" void kernel_launch(void* const* d_in, const int* in_sizes, int n_in,
                              void* d_out, int out_size, void* d_ws, size_t ws_size,
                              hipStream_t stream)
{
    const float* cls  = (const float*)d_in[0];
    const float* comp = (const float*)d_in[1];
    const float* breg = (const float*)d_in[2];
    const float* prop = (const float*)d_in[3];
    float* ws  = (float*)d_ws;
    float* out = (float*)d_out;

    hipLaunchKernelGGL(prep_kernel, dim3(NPROP), dim3(64), 0, stream,
                       cls, comp, ws, out, out_size);
    hipLaunchKernelGGL(nms_kernel, dim3(NFG), dim3(64), 0, stream,
                       cls, breg, prop, ws);
    hipLaunchKernelGGL(topk_kernel, dim3(TKB), dim3(256), 0, stream, ws, out);
}

// Round 4
// 36.901 us; speedup vs baseline: 3.0583x; 2.2711x over previous
//
#include <hip/hip_runtime.h>
#include <math.h>

#define NCLS 81
#define NFG 80
#define KCOMP 11
#define NPROP 1000
#define MAXC 6144
#define DETS 100
#define RMAX 1024

// workspace layout (float indices)
#define WS_M      0                 // [1000] row max of class logits
#define WS_S      1000              // [1000] softmax denom
#define WS_COMPS  2000              // [1000] comp score
#define WS_COMPI  3000              // [1000] comp idx (as float)
#define WS_CAND   4096              // [MAXC][8]: key_lo, key_hi, x1,y1,x2,y2, comp_s, comp_i
#define WS_CNT    (4096 + MAXC*8)   // int counter

__global__ __launch_bounds__(64) void prep_kernel(
    const float* __restrict__ cls_logits,
    const float* __restrict__ comp_logits,
    float* __restrict__ ws,
    float* __restrict__ out, int out_size)
{
    int n = blockIdx.x;
    int lane = threadIdx.x;
    if (n == 0 && lane == 0) ((int*)ws)[WS_CNT] = 0;
    // output defaults (padded slots): score slots -1, everything else 0
    if (n < 13) {
        int oi = n * 64 + lane;
        if (oi < out_size) out[oi] = (oi >= 400 && oi < 500) ? -1.0f : 0.0f;
    }

    // ---- class softmax stats (81 values; lanes hold c=lane and c=lane+64) ----
    float x0 = cls_logits[n * NCLS + lane];
    float x1 = (lane < NCLS - 64) ? cls_logits[n * NCLS + 64 + lane] : -INFINITY;
    float m = fmaxf(x0, x1);
    for (int off = 32; off; off >>= 1) m = fmaxf(m, __shfl_xor(m, off));
    float s = expf(x0 - m) + ((lane < NCLS - 64) ? expf(x1 - m) : 0.0f);
    for (int off = 32; off; off >>= 1) s += __shfl_xor(s, off);
    if (lane == 0) { ws[WS_M + n] = m; ws[WS_S + n] = s; }

    // ---- component softmax + fg max/argmax (first occurrence) ----
    float y = (lane < KCOMP) ? comp_logits[n * KCOMP + lane] : -INFINITY;
    float mc = y;
    for (int off = 32; off; off >>= 1) mc = fmaxf(mc, __shfl_xor(mc, off));
    float ec = (lane < KCOMP) ? expf(y - mc) : 0.0f;
    float sc = ec;
    for (int off = 32; off; off >>= 1) sc += __shfl_xor(sc, off);
    float p = (lane >= 1 && lane < KCOMP) ? ec / sc : -1.0f;
    int ci = lane;
    for (int off = 32; off; off >>= 1) {
        float po = __shfl_xor(p, off);
        int   io = __shfl_xor(ci, off);
        if (po > p || (po == p && io < ci)) { p = po; ci = io; }
    }
    if (lane == 0) {
        ws[WS_COMPS + n] = p;
        ws[WS_COMPI + n] = (float)ci;
    }
}

__global__ __launch_bounds__(64) void nms_kernel(
    const float* __restrict__ cls_logits,
    const float* __restrict__ boxreg,
    const float* __restrict__ props,
    float* __restrict__ ws)
{
    __shared__ float ls[1024];
    __shared__ int   ln[1024];
    __shared__ float ss[1024];
    __shared__ int   sn[1024];
    __shared__ float sb[1024][4];

    int cfg  = blockIdx.x;   // class c = cfg + 1
    int c    = cfg + 1;
    int lane = threadIdx.x;

    // ---- compute probs for all 16 rounds first (16 independent loads in flight) ----
    float pv[16];
#pragma unroll
    for (int t = 0; t < 16; ++t) {
        int n = t * 64 + lane;
        if (n < NPROP) {
            float x = cls_logits[n * NCLS + c];
            pv[t] = expf(x - ws[WS_M + n]) / ws[WS_S + n];
        } else {
            pv[t] = 0.0f;
        }
    }

    // ---- compact valid entries (preserves original n-order) ----
    int cnt = 0;
#pragma unroll
    for (int t = 0; t < 16; ++t) {
        int n = t * 64 + lane;
        bool v = (n < NPROP) && (pv[t] > 0.05f);
        unsigned long long bm = __ballot(v);
        if (v) {
            int pos = cnt + __popcll(bm & ((1ull << lane) - 1ull));
            ls[pos] = pv[t]; ln[pos] = n;
        }
        cnt += __popcll(bm);
    }
    int M = cnt;
    __syncthreads();

    // ---- rank sort (descending score, ties by original n order) ----
    for (int i = lane; i < M; i += 64) {
        float si = ls[i];
        int r = 0;
        for (int j = 0; j < M; ++j) {
            float sj = ls[j];
            r += (int)((sj > si) | ((sj == si) & (j < i)));
        }
        ss[r] = si; sn[r] = ln[i];
    }
    __syncthreads();

    // ---- decode + clip boxes for the M sorted candidates only ----
    const float CLIPV = 4.135166556742356f; // log(1000/16)
    for (int p = lane; p < M; p += 64) {
        int n = sn[p];
        float4 r4 = ((const float4*)boxreg)[n * NCLS + c];
        float4 pr = ((const float4*)props)[n];
        float w  = pr.z - pr.x + 1.0f, h = pr.w - pr.y + 1.0f;
        float cx = pr.x + 0.5f * w,  cy = pr.y + 0.5f * h;
        float dx = r4.x / 10.0f, dy = r4.y / 10.0f;
        float dw = fminf(r4.z / 5.0f, CLIPV), dh = fminf(r4.w / 5.0f, CLIPV);
        float pcx = dx * w + cx, pcy = dy * h + cy;
        float pw = expf(dw) * w, ph = expf(dh) * h;
        sb[p][0] = fminf(fmaxf(pcx - 0.5f * pw, 0.0f), 1332.0f);
        sb[p][1] = fminf(fmaxf(pcy - 0.5f * ph, 0.0f), 799.0f);
        sb[p][2] = fminf(fmaxf(pcx + 0.5f * pw - 1.0f, 0.0f), 1332.0f);
        sb[p][3] = fminf(fmaxf(pcy + 0.5f * ph - 1.0f, 0.0f), 799.0f);
    }
    __syncthreads();

    // ---- greedy NMS: keep bits distributed, slot p -> lane p%64, bit p/64 ----
    unsigned int keep = 0;
    for (int k = 0; k < 16; ++k) {
        int p = lane + (k << 6);
        if (p < M) keep |= (1u << k);
    }
    for (int i = 0; i < M; ++i) {
        unsigned int ki = __shfl(keep, i & 63);
        if (!((ki >> (i >> 6)) & 1u)) continue;
        float ax1 = sb[i][0], ay1 = sb[i][1], ax2 = sb[i][2], ay2 = sb[i][3];
        float aarea = (ax2 - ax1 + 1.0f) * (ay2 - ay1 + 1.0f);
        unsigned int km = keep;
        while (km) {
            int k = __ffs(km) - 1; km &= km - 1;
            int p = lane + (k << 6);
            if (p <= i) continue;
            float bx1 = sb[p][0], by1 = sb[p][1], bx2 = sb[p][2], by2 = sb[p][3];
            float barea = (bx2 - bx1 + 1.0f) * (by2 - by1 + 1.0f);
            float lx = fmaxf(ax1, bx1), ly = fmaxf(ay1, by1);
            float rx = fminf(ax2, bx2), ry = fminf(ay2, by2);
            float iw = fmaxf(rx - lx + 1.0f, 0.0f), ih = fmaxf(ry - ly + 1.0f, 0.0f);
            float inter = iw * ih;
            float iou = inter / (aarea + barea - inter);
            if (iou > 0.5f) keep &= ~(1u << k);
        }
    }

    // ---- append survivor records to the global candidate list ----
    int* cntp = &((int*)ws)[WS_CNT];
    for (int k = 0; k < 16; ++k) {
        int p = lane + (k << 6);
        bool v = (p < M) && ((keep >> k) & 1u);
        unsigned long long bm = __ballot(v);
        int cm = __popcll(bm);
        int base = 0;
        if (lane == 0 && cm) base = atomicAdd(cntp, cm);
        base = __shfl(base, 0);
        if (v) {
            int idx = base + __popcll(bm & ((1ull << lane) - 1ull));
            if (idx < MAXC) {
                int n = sn[p];
                // meta = flat_sorted_index << 10 | original_n (reference tie-break)
                unsigned int meta = (unsigned int)(((cfg * NPROP + p) << 10) | n);
                // 64-bit sort key: score bits (positive floats order-isomorphic)
                // in high word, ~meta in low word -> larger key = better.
                unsigned int khi = __float_as_uint(ss[p]);
                unsigned int klo = ~meta;
                float4* cp = (float4*)&ws[WS_CAND + idx * 8];
                cp[0] = make_float4(__uint_as_float(klo), __uint_as_float(khi),
                                    sb[p][0], sb[p][1]);
                cp[1] = make_float4(sb[p][2], sb[p][3],
                                    ws[WS_COMPS + n], ws[WS_COMPI + n]);
            }
        }
    }
}

// Histogram-select top-100: O(K) histogram + O(R^2) exact rank on the ~R<=300
// keys that can possibly be in the top 100. Single block.
__global__ __launch_bounds__(1024) void topk_kernel(const float* __restrict__ ws,
                                                    float* __restrict__ out)
{
    __shared__ unsigned long long kk[MAXC];    // 48 KB
    __shared__ int hist[1024];                 // counts -> suffix counts (in place)
    __shared__ unsigned long long rkey[RMAX];  // candidate keys with possible rank<100
    __shared__ int ridx[RMAX];
    __shared__ int rcount;

    int K = ((const int*)ws)[WS_CNT];
    if (K > MAXC) K = MAXC;
    int tid = threadIdx.x;

    if (tid < 1024) hist[tid] = 0;
    if (tid == 0) rcount = 0;
    __syncthreads();

    // ---- load keys + histogram top-16 score bits (monotonic buckets) ----
    // score in (0.05, 1] -> float bits in [0x3D4CCCCE, 0x3F800000],
    // (bits>>16) in [15692, 16256]; map to bucket (bits>>16) - 15360 in [332, 896].
    for (int j = tid; j < K; j += 1024) {
        unsigned long long k = *(const unsigned long long*)&ws[WS_CAND + j * 8];
        kk[j] = k;
        int b = (int)((unsigned int)(k >> 48)) - 15360;
        b = b < 0 ? 0 : (b > 1023 ? 1023 : b);
        atomicAdd(&hist[b], 1);
    }
    __syncthreads();

    // ---- wave 0: in-place suffix count S[b] = #keys in buckets > b ----
    if (tid < 64) {
        int base = tid * 16;
        int tot = 0;
#pragma unroll
        for (int t = 0; t < 16; ++t) tot += hist[base + t];
        // excl = sum of totals of lanes > tid
        int s = tot;
        for (int off = 1; off < 64; off <<= 1) {
            int o = __shfl_down(s, off);
            if (tid + off < 64) s += o;
        }
        int run = s - tot;  // suffix of higher lanes
        for (int t = 15; t >= 0; --t) {
            int h = hist[base + t];
            hist[base + t] = run;
            run += h;
        }
    }
    __syncthreads();

    // ---- compact R = keys whose bucket's higher-count < DETS ----
    for (int j = tid; j < K; j += 1024) {
        unsigned long long k = kk[j];
        int b = (int)((unsigned int)(k >> 48)) - 15360;
        b = b < 0 ? 0 : (b > 1023 ? 1023 : b);
        if (hist[b] < DETS) {
            int pos = atomicAdd(&rcount, 1);
            if (pos < RMAX) { rkey[pos] = k; ridx[pos] = j; }
        }
    }
    __syncthreads();
    int R = rcount < RMAX ? rcount : RMAX;

    // ---- exact rank within R (== global rank, by bucket monotonicity) ----
    for (int i = tid; i < R; i += 1024) {
        unsigned long long ki = rkey[i];
        int r = 0;
        int j = 0;
        for (; j + 16 <= R; j += 16) {
            unsigned long long a[16];
#pragma unroll
            for (int t = 0; t < 16; ++t) a[t] = rkey[j + t];
#pragma unroll
            for (int t = 0; t < 16; ++t) r += (int)(a[t] > ki);
        }
        for (; j < R; ++j) r += (int)(rkey[j] > ki);

        if (r < DETS) {
            const float4* cp = (const float4*)&ws[WS_CAND + ridx[i] * 8];
            float4 a = cp[0], b = cp[1];
            unsigned int meta = ~__float_as_uint(a.x);
            float score = a.y;  // key_hi bits == score bits
            out[r * 4 + 0] = a.z;
            out[r * 4 + 1] = a.w;
            out[r * 4 + 2] = b.x;
            out[r * 4 + 3] = b.y;
            out[400 + r] = score;
            out[500 + r] = b.z;
            out[600 + r] = (float)((meta >> 10) / NPROP + 1);
            out[700 + r] = b.w;
        }
    }
}

extern "C" void kernel_launch(void* const* d_in, const int* in_sizes, int n_in,
                              void* d_out, int out_size, void* d_ws, size_t ws_size,
                              hipStream_t stream)
{
    const float* cls  = (const float*)d_in[0];
    const float* comp = (const float*)d_in[1];
    const float* breg = (const float*)d_in[2];
    const float* prop = (const float*)d_in[3];
    float* ws  = (float*)d_ws;
    float* out = (float*)d_out;

    hipLaunchKernelGGL(prep_kernel, dim3(NPROP), dim3(64), 0, stream,
                       cls, comp, ws, out, out_size);
    hipLaunchKernelGGL(nms_kernel, dim3(NFG), dim3(64), 0, stream,
                       cls, breg, prop, ws);
    hipLaunchKernelGGL(topk_kernel, dim3(1), dim3(1024), 0, stream, ws, out);
}